// Round 2
// baseline (480.358 us; speedup 1.0000x reference)
//
#include <hip/hip_runtime.h>
#include <stdint.h>

// Problem constants
#define BB   256
#define NN   2048
#define MM   64
#define CC   512
#define OUTD 198

#define MAGIC1 0x1B873593u
#define MAGIC2 0xC2B2AE35u

typedef float vf4 __attribute__((ext_vector_type(4)));

__device__ __forceinline__ float softplusf(float x) {
    return x > 20.f ? x : log1pf(expf(x));
}
__device__ __forceinline__ float sigmoidf(float x) {
    return 1.f / (1.f + expf(-x));
}

// ---------------------------------------------------------------------------
// Pair-split fused NTM write head: TWO blocks per batch (grid 512 x 1024).
// Block pair (2b, 2b+1) -> batch b, halves 0/1 of the N=2048 rows.
// Per block:
//   ph0 : controller matvec + activations (duplicated in both halves; W is
//         L2-resident, ~405KB/block -> ~6us aggregate, cheap)
//   ph1 : content logits for OUR 1024 rows (262KB HBM read) -> LDS + global
//   sync: release/acquire flag handshake with partner, import its 4KB logits
//   ph2 : full softmax->gate->shift->sharpen->normalize chain (duplicated)
//   ph3 : erase/add write for OUR 1024 rows (262KB LLC read + 262KB HBM write)
// 2 blocks/CU x 16 waves = 32 waves/CU (100% occupancy); the two co-resident
// blocks are independent, so one block's barriers/compute phases are covered
// by the other block's memory stream.
// Flags live in ws and are memset to 0 before every launch, so the handshake
// is real on every graph replay; pairs are adjacent block IDs and all 512
// blocks fit co-resident (20KB LDS, <=64 VGPR), so the spin cannot deadlock.
// ---------------------------------------------------------------------------
__global__ __launch_bounds__(1024, 8) void k_fused(
        const float* __restrict__ h, const float* __restrict__ Wm,
        const float* __restrict__ bias, const float* __restrict__ w_prev,
        const float* __restrict__ mem, float* __restrict__ w_out,
        float* __restrict__ mem_out, float* __restrict__ ws) {
    __shared__ float hs[CC];
    __shared__ float os[OUTD];
    __shared__ __align__(16) float kk[MM];   // k + 1e-16
    __shared__ __align__(16) float ee[MM];   // sigmoid(e)
    __shared__ __align__(16) float aa[MM];
    __shared__ float sc[8];                  // 0:beta 1:g 2:gamma 3:knorm 4..6:s
    __shared__ float lgs[NN];                // full logits, later final-w (our half)
    __shared__ float wg[NN];                 // gated weights (full)
    __shared__ float red[16];

    const int pb = blockIdx.x;
    const int b  = pb >> 1;
    const int hf = pb & 1;
    const int t  = threadIdx.x;
    const int lane = t & 63;
    const int wid  = t >> 6;

    float* glg = ws;                                        // [BB][NN] logits
    unsigned* flags = (unsigned*)(ws + (size_t)BB * NN);    // [2][512]

    // ---- phase 0: controller projection (198x512 matvec, duplicated) -----
    if (t < CC) hs[t] = h[(size_t)b * CC + t];
    __syncthreads();

    if (t < 4 * OUTD) {                      // 4 lanes per output row
        const int row = t >> 2, l4 = t & 3;
        const float* wr = Wm + (size_t)row * CC + 4 * l4;
        float acc = 0.f;
        #pragma unroll
        for (int c = 0; c < CC; c += 16) {
            const float4 p = *(const float4*)(wr + c);
            const int hb = c + 4 * l4;
            acc += p.x * hs[hb] + p.y * hs[hb + 1] + p.z * hs[hb + 2] + p.w * hs[hb + 3];
        }
        acc += __shfl_xor(acc, 1, 64);
        acc += __shfl_xor(acc, 2, 64);
        if (l4 == 0) os[row] = acc + bias[row];
    }
    __syncthreads();

    // ---- phase 0b: split + activations -----------------------------------
    if (t < 64) {
        const float kv = os[t] + 1e-16f;
        kk[t] = kv;
        float ss = kv * kv;
        #pragma unroll
        for (int off = 32; off; off >>= 1) ss += __shfl_xor(ss, off, 64);
        if (t == 0) sc[3] = sqrtf(ss);       // ||k + 1e-16||
    } else if (t < 128) {
        const int m = t - 64;
        ee[m] = sigmoidf(os[70 + m]);
        aa[m] = os[134 + m];
    } else if (t == 128) {
        sc[0] = softplusf(os[64]);           // beta
    } else if (t == 129) {
        sc[1] = sigmoidf(os[65]);            // g
    } else if (t == 130) {
        sc[2] = 1.f + softplusf(os[69]);     // gamma
    } else if (t == 131) {                   // 3-way softmax for shift weights
        const float x0 = os[66], x1 = os[67], x2 = os[68];
        const float mx = fmaxf(x0, fmaxf(x1, x2));
        const float e0 = expf(x0 - mx), e1 = expf(x1 - mx), e2 = expf(x2 - mx);
        const float inv = 1.f / (e0 + e1 + e2);
        sc[4] = e0 * inv; sc[5] = e1 * inv; sc[6] = e2 * inv;
    }
    __syncthreads();

    // ---- phase 1: content logits for OUR half ----------------------------
    {
        const int l = t & 15, grp = t >> 4;  // 64 groups of 16 lanes
        const float kv0 = kk[4 * l + 0], kv1 = kk[4 * l + 1];
        const float kv2 = kk[4 * l + 2], kv3 = kk[4 * l + 3];
        const float beta = sc[0], knorm = sc[3];
        const float* mb = mem + ((size_t)b * NN + hf * 1024) * MM;
        #pragma unroll 4
        for (int it = 0; it < 16; ++it) {
            const int rl = it * 64 + grp;    // wave reads 4 consecutive rows = 1KB
            const float4 p = *(const float4*)(mb + (size_t)rl * MM + 4 * l);
            const float m0 = p.x + 1e-16f, m1 = p.y + 1e-16f;
            const float m2 = p.z + 1e-16f, m3 = p.w + 1e-16f;
            float dot = m0 * kv0 + m1 * kv1 + m2 * kv2 + m3 * kv3;
            float ss  = m0 * m0 + m1 * m1 + m2 * m2 + m3 * m3;
            #pragma unroll
            for (int off = 1; off < 16; off <<= 1) {
                dot += __shfl_xor(dot, off, 64);
                ss  += __shfl_xor(ss,  off, 64);
            }
            if (l == 0)
                lgs[hf * 1024 + rl] = beta * dot / fmaxf(sqrtf(ss) * knorm, 1e-8f);
        }
    }
    __syncthreads();

    // ---- publish our half + handshake with partner -----------------------
    glg[(size_t)b * NN + hf * 1024 + t] = lgs[hf * 1024 + t];
    __threadfence();
    __syncthreads();
    if (t == 0) {
        __hip_atomic_store(&flags[pb],       MAGIC1, __ATOMIC_RELEASE, __HIP_MEMORY_SCOPE_AGENT);
        __hip_atomic_store(&flags[512 + pb], MAGIC2, __ATOMIC_RELEASE, __HIP_MEMORY_SCOPE_AGENT);
        while (__hip_atomic_load(&flags[pb ^ 1], __ATOMIC_ACQUIRE, __HIP_MEMORY_SCOPE_AGENT) != MAGIC1 ||
               __hip_atomic_load(&flags[512 + (pb ^ 1)], __ATOMIC_ACQUIRE, __HIP_MEMORY_SCOPE_AGENT) != MAGIC2)
            __builtin_amdgcn_s_sleep(2);
    }
    __syncthreads();
    {   // import partner half with agent-scope loads (bypass stale caches)
        const int ph = hf ^ 1;
        const float* src = glg + (size_t)b * NN + ph * 1024;
        lgs[ph * 1024 + t] = __hip_atomic_load(&src[t], __ATOMIC_RELAXED, __HIP_MEMORY_SCOPE_AGENT);
    }
    __syncthreads();

    // ---- phase 2: softmax -> gate -> shift -> sharpen -> normalize -------
    const float g = sc[1], gamma = sc[2];
    const float s0 = sc[4], s1 = sc[5], s2 = sc[6];

    float v0 = lgs[t], v1 = lgs[t + 1024];
    float lmax = fmaxf(v0, v1);
    #pragma unroll
    for (int off = 32; off; off >>= 1) lmax = fmaxf(lmax, __shfl_xor(lmax, off, 64));
    if (lane == 0) red[wid] = lmax;
    __syncthreads();
    float mx = red[0];
    #pragma unroll
    for (int i = 1; i < 16; ++i) mx = fmaxf(mx, red[i]);
    __syncthreads();

    v0 = expf(v0 - mx); v1 = expf(v1 - mx);
    float lsum = v0 + v1;
    #pragma unroll
    for (int off = 32; off; off >>= 1) lsum += __shfl_xor(lsum, off, 64);
    if (lane == 0) red[wid] = lsum;
    __syncthreads();
    float tot = 0.f;
    #pragma unroll
    for (int i = 0; i < 16; ++i) tot += red[i];
    __syncthreads();
    const float inv = 1.f / tot;

    wg[t]        = g * (v0 * inv) + (1.f - g) * w_prev[(size_t)b * NN + t];
    wg[t + 1024] = g * (v1 * inv) + (1.f - g) * w_prev[(size_t)b * NN + t + 1024];
    __syncthreads();

    float ws0, ws1;
    {
        const int n0 = t;
        const float wt0 = wg[(n0 + NN - 1) & (NN - 1)] * s0 + wg[n0] * s1
                        + wg[(n0 + 1) & (NN - 1)] * s2;
        ws0 = (wt0 > 0.f) ? exp2f(gamma * log2f(wt0)) : 0.f;
        const int n1 = t + 1024;
        const float wt1 = wg[(n1 - 1) & (NN - 1)] * s0 + wg[n1] * s1
                        + wg[(n1 + 1) & (NN - 1)] * s2;
        ws1 = (wt1 > 0.f) ? exp2f(gamma * log2f(wt1)) : 0.f;
    }
    float psum = ws0 + ws1;
    #pragma unroll
    for (int off = 32; off; off >>= 1) psum += __shfl_xor(psum, off, 64);
    if (lane == 0) red[wid] = psum;
    __syncthreads();
    float ptot = 0.f;
    #pragma unroll
    for (int i = 0; i < 16; ++i) ptot += red[i];
    const float invp = 1.f / (ptot + 1e-16f);

    // final w for OUR half element (hf*1024 + t); reuse lgs[0..1024)
    const float wf = (hf ? ws1 : ws0) * invp;
    lgs[t] = wf;
    w_out[(size_t)b * NN + hf * 1024 + t] = wf;
    __syncthreads();

    // ---- phase 3: erase/add write for OUR half ---------------------------
    {
        const int m0 = 4 * (t & 15);          // fixed per thread across iters
        const vf4 ev = *(const vf4*)(ee + m0);
        const vf4 av = *(const vf4*)(aa + m0);
        const size_t base = ((size_t)b * NN + hf * 1024) * MM + 4 * t;
        const float* mb = mem + base;
        float* ob = mem_out + base;
        #pragma unroll 4
        for (int it = 0; it < 16; ++it) {
            const float w = lgs[it * 64 + (t >> 4)];   // LDS broadcast
            const float4 p = *(const float4*)(mb + (size_t)it * 4096);
            vf4 o;
            o.x = p.x * (1.f - w * ev.x) + w * av.x;
            o.y = p.y * (1.f - w * ev.y) + w * av.y;
            o.z = p.z * (1.f - w * ev.z) + w * av.z;
            o.w = p.w * (1.f - w * ev.w) + w * av.w;
            __builtin_nontemporal_store(o, (vf4*)(ob + (size_t)it * 4096));
        }
    }
}

extern "C" void kernel_launch(void* const* d_in, const int* in_sizes, int n_in,
                              void* d_out, int out_size, void* d_ws, size_t ws_size,
                              hipStream_t stream) {
    const float* h      = (const float*)d_in[0];
    const float* w_prev = (const float*)d_in[1];
    const float* memory = (const float*)d_in[2];
    const float* W      = (const float*)d_in[3];
    const float* bias   = (const float*)d_in[4];
    float* out = (float*)d_out;
    float* ws  = (float*)d_ws;

    float* w_out   = out;                       // [B,N]
    float* mem_out = out + (size_t)BB * NN;     // [B,N,M]

    // clear the pair-handshake flags so every graph replay does a real sync
    hipMemsetAsync(ws + (size_t)BB * NN, 0, 2 * 512 * sizeof(unsigned), stream);
    k_fused<<<BB * 2, 1024, 0, stream>>>(h, W, bias, w_prev, memory, w_out, mem_out, ws);
}

// Round 3
// 283.103 us; speedup vs baseline: 1.6968x; 1.6968x over previous
//
#include <hip/hip_runtime.h>
#include <stdint.h>

// Problem constants
#define BB   256
#define NN   2048
#define MM   64
#define CC   512
#define OUTD 198

// Workspace layout (floats)
#define PSTRIDE   256                       // per-batch param block
#define K_OFF     0                         // k[64]
#define E_OFF     64                        // e[64] (post-sigmoid)
#define A_OFF     128                       // a[64]
#define BETA_OFF  192
#define G_OFF     193
#define GAMMA_OFF 194
#define S_OFF     195                       // s[3]
#define KNORM_OFF 198
#define LOGITS_OFF (BB * PSTRIDE)           // [B,N] fp32 logits

typedef float vf4 __attribute__((ext_vector_type(4)));

__device__ __forceinline__ float softplusf(float x) {
    return x > 20.f ? x : log1pf(expf(x));
}
__device__ __forceinline__ float sigmoidf(float x) {
    return 1.f / (1.f + expf(-x));
}

// ---------------------------------------------------------------------------
// Kernel 1: controller projection o = h @ W^T + b, split + activations.
// One block per batch, 256 threads. W (405 KB) is L2/LLC-cached across blocks.
// (Proven in round 0 — unchanged.)
// ---------------------------------------------------------------------------
__global__ __launch_bounds__(256) void k_ctrl(
        const float* __restrict__ h, const float* __restrict__ Wm,
        const float* __restrict__ bias, float* __restrict__ ws) {
    __shared__ float hs[CC];
    __shared__ float os[OUTD];
    const int b = blockIdx.x, t = threadIdx.x;

    for (int c = t; c < CC; c += 256) hs[c] = h[b * CC + c];
    __syncthreads();

    if (t < OUTD) {
        const float* wr = Wm + (size_t)t * CC;
        float acc = 0.f;
        #pragma unroll 8
        for (int c = 0; c < CC; c += 4) {
            float4 p = *(const float4*)(wr + c);
            acc += p.x * hs[c+0] + p.y * hs[c+1] + p.z * hs[c+2] + p.w * hs[c+3];
        }
        os[t] = acc + bias[t];
    }
    __syncthreads();

    float* P = ws + (size_t)b * PSTRIDE;
    if (t < 64) {
        P[K_OFF + t] = os[t];
    } else if (t == 64) {
        P[BETA_OFF] = softplusf(os[64]);
    } else if (t == 65) {
        P[G_OFF] = sigmoidf(os[65]);
    } else if (t == 66) {   // 3-way softmax for shift weights
        float x0 = os[66], x1 = os[67], x2 = os[68];
        float mx = fmaxf(x0, fmaxf(x1, x2));
        float e0 = expf(x0 - mx), e1 = expf(x1 - mx), e2 = expf(x2 - mx);
        float inv = 1.f / (e0 + e1 + e2);
        P[S_OFF + 0] = e0 * inv; P[S_OFF + 1] = e1 * inv; P[S_OFF + 2] = e2 * inv;
    } else if (t == 69) {
        P[GAMMA_OFF] = 1.f + softplusf(os[69]);
    } else if (t >= 70 && t < 134) {
        P[E_OFF + (t - 70)] = sigmoidf(os[t]);
    } else if (t >= 134 && t < 198) {
        P[A_OFF + (t - 134)] = os[t];
    } else if (t == 198) {  // ||k + 1e-16||
        float ss = 0.f;
        for (int i = 0; i < MM; ++i) { float kv = os[i] + 1e-16f; ss += kv * kv; }
        P[KNORM_OFF] = sqrtf(ss);
    }
}

// ---------------------------------------------------------------------------
// Kernel 2: content-addressing logits. 8 blocks/batch, 256 rows each,
// 16 lanes/row x float4 loads, xor-shuffle reduce. Grid 2048 = 8 blocks/CU;
// __launch_bounds__(256,8) pins 32 waves/CU (100% occupancy). Normal
// (caching) loads on purpose: pulls `memory` into LLC for k_addrwrite.
// ---------------------------------------------------------------------------
__global__ __launch_bounds__(256, 8) void k_logits(
        const float* __restrict__ mem, float* __restrict__ ws) {
    const int b = blockIdx.x >> 3;
    const int chunk = blockIdx.x & 7;
    const int t = threadIdx.x;
    const int l = t & 15;       // lane within 16-group
    const int grp = t >> 4;     // 16 groups/block

    const float* P = ws + (size_t)b * PSTRIDE;
    float kv[4];
    #pragma unroll
    for (int i = 0; i < 4; ++i) kv[i] = P[K_OFF + 4 * l + i] + 1e-16f;
    const float beta  = P[BETA_OFF];
    const float knorm = P[KNORM_OFF];
    float* lg = ws + LOGITS_OFF + (size_t)b * NN;

    const int row0 = chunk * 256;
    #pragma unroll
    for (int it = 0; it < 16; ++it) {
        const int row = row0 + it * 16 + grp;
        float4 p = *(const float4*)(mem + ((size_t)b * NN + row) * MM + 4 * l);
        float m0 = p.x + 1e-16f, m1 = p.y + 1e-16f, m2 = p.z + 1e-16f, m3 = p.w + 1e-16f;
        float dot = m0 * kv[0] + m1 * kv[1] + m2 * kv[2] + m3 * kv[3];
        float ss  = m0 * m0 + m1 * m1 + m2 * m2 + m3 * m3;
        #pragma unroll
        for (int off = 1; off < 16; off <<= 1) {
            dot += __shfl_xor(dot, off, 64);
            ss  += __shfl_xor(ss,  off, 64);
        }
        if (l == 0) {
            float denom = fmaxf(sqrtf(ss) * knorm, 1e-8f);
            lg[row] = beta * dot / denom;
        }
    }
}

// ---------------------------------------------------------------------------
// Kernel 3: softmax -> gate -> shift -> sharpen -> normalize, then the
// erase/add memory write for this block's QUARTER of rows. 4 blocks/batch
// (grid 1024 x 512 thr = 4 blocks/CU = 32 waves = 100% occupancy). The
// softmax chain is duplicated x4 per batch (logit row is 8 KB, L2/LLC-hot
// from k_logits; chain is VALU/LDS-cheap) — in exchange there is NO global
// drain between addressing and writing, no cross-block sync, and blocks at
// different phases overlap each other's memory streams on the same CU.
// Nontemporal stores keep mem_out from evicting the LLC-resident `memory`.
// ---------------------------------------------------------------------------
__global__ __launch_bounds__(512, 8) void k_addrwrite(
        const float* __restrict__ w_prev, const float* __restrict__ ws,
        const float* __restrict__ mem, float* __restrict__ w_out,
        float* __restrict__ mem_out) {
    __shared__ float buf[NN];     // w_g
    __shared__ float wfin[NN];    // final w
    __shared__ float red[8];
    const int b = blockIdx.x >> 2;
    const int q = blockIdx.x & 3;
    const int t = threadIdx.x;
    const int lane = t & 63, wid = t >> 6;

    const float* P  = ws + (size_t)b * PSTRIDE;
    const float* lg = ws + LOGITS_OFF + (size_t)b * NN;

    const float g  = P[G_OFF];
    const float s0 = P[S_OFF + 0], s1 = P[S_OFF + 1], s2 = P[S_OFF + 2];
    const float gamma = P[GAMMA_OFF];

    float v[4];
    float lmax = -1e30f;
    #pragma unroll
    for (int i = 0; i < 4; ++i) { v[i] = lg[t + i * 512]; lmax = fmaxf(lmax, v[i]); }
    #pragma unroll
    for (int off = 32; off; off >>= 1) lmax = fmaxf(lmax, __shfl_xor(lmax, off, 64));
    if (lane == 0) red[wid] = lmax;
    __syncthreads();
    float mx = red[0];
    #pragma unroll
    for (int i = 1; i < 8; ++i) mx = fmaxf(mx, red[i]);
    __syncthreads();

    float lsum = 0.f;
    #pragma unroll
    for (int i = 0; i < 4; ++i) { v[i] = expf(v[i] - mx); lsum += v[i]; }
    #pragma unroll
    for (int off = 32; off; off >>= 1) lsum += __shfl_xor(lsum, off, 64);
    if (lane == 0) red[wid] = lsum;
    __syncthreads();
    float tot = 0.f;
    #pragma unroll
    for (int i = 0; i < 8; ++i) tot += red[i];
    __syncthreads();
    const float inv = 1.f / tot;

    #pragma unroll
    for (int i = 0; i < 4; ++i) {
        const int n = t + i * 512;
        buf[n] = g * (v[i] * inv) + (1.f - g) * w_prev[(size_t)b * NN + n];
    }
    __syncthreads();

    float psum = 0.f;
    #pragma unroll
    for (int i = 0; i < 4; ++i) {
        const int n = t + i * 512;
        const float wt = buf[(n + NN - 1) & (NN - 1)] * s0 + buf[n] * s1
                       + buf[(n + 1) & (NN - 1)] * s2;
        v[i] = (wt > 0.f) ? exp2f(gamma * log2f(wt)) : 0.f;
        psum += v[i];
    }
    #pragma unroll
    for (int off = 32; off; off >>= 1) psum += __shfl_xor(psum, off, 64);
    if (lane == 0) red[wid] = psum;
    __syncthreads();
    float ptot = 0.f;
    #pragma unroll
    for (int i = 0; i < 8; ++i) ptot += red[i];
    const float invp = 1.f / (ptot + 1e-16f);

    #pragma unroll
    for (int i = 0; i < 4; ++i) wfin[t + i * 512] = v[i] * invp;
    // our quarter of w: n = q*512 + t corresponds to i == q
    w_out[(size_t)b * NN + q * 512 + t] = v[q] * invp;
    __syncthreads();

    // ---- erase/add write for rows [q*512, q*512+512) ----------------------
    {
        const int m0 = 4 * (t & 15);          // fixed per thread across iters
        const vf4 ev = *(const vf4*)(P + E_OFF + m0);
        const vf4 av = *(const vf4*)(P + A_OFF + m0);
        const size_t base = ((size_t)b * NN + (size_t)q * 512) * MM + 4 * t;
        const float* mb = mem + base;
        float* ob = mem_out + base;
        #pragma unroll 4
        for (int it = 0; it < 16; ++it) {
            // element index in quarter = it*2048 + 4t -> row = it*32 + (t>>4)
            const float w = wfin[q * 512 + it * 32 + (t >> 4)];   // LDS broadcast
            const float4 p = *(const float4*)(mb + (size_t)it * 2048);
            vf4 o;
            o.x = p.x * (1.f - w * ev.x) + w * av.x;
            o.y = p.y * (1.f - w * ev.y) + w * av.y;
            o.z = p.z * (1.f - w * ev.z) + w * av.z;
            o.w = p.w * (1.f - w * ev.w) + w * av.w;
            __builtin_nontemporal_store(o, (vf4*)(ob + (size_t)it * 2048));
        }
    }
}

extern "C" void kernel_launch(void* const* d_in, const int* in_sizes, int n_in,
                              void* d_out, int out_size, void* d_ws, size_t ws_size,
                              hipStream_t stream) {
    const float* h      = (const float*)d_in[0];
    const float* w_prev = (const float*)d_in[1];
    const float* memory = (const float*)d_in[2];
    const float* W      = (const float*)d_in[3];
    const float* bias   = (const float*)d_in[4];
    float* out = (float*)d_out;
    float* ws  = (float*)d_ws;

    float* w_out   = out;                       // [B,N]
    float* mem_out = out + (size_t)BB * NN;     // [B,N,M]

    k_ctrl     <<<BB,     256, 0, stream>>>(h, W, bias, ws);
    k_logits   <<<BB * 8, 256, 0, stream>>>(memory, ws);
    k_addrwrite<<<BB * 4, 512, 0, stream>>>(w_prev, ws, memory, w_out, mem_out);
}

// Round 4
// 269.001 us; speedup vs baseline: 1.7857x; 1.0524x over previous
//
#include <hip/hip_runtime.h>
#include <stdint.h>

// Problem constants
#define BB   256
#define NN   2048
#define MM   64
#define CC   512
#define OUTD 198

typedef float vf4 __attribute__((ext_vector_type(4)));

__device__ __forceinline__ float softplusf(float x) {
    return x > 20.f ? x : log1pf(expf(x));
}
__device__ __forceinline__ float sigmoidf(float x) {
    return 1.f / (1.f + expf(-x));
}

// ---------------------------------------------------------------------------
// Fully fused NTM write head: one block per batch, 1024 threads (16 waves).
// Round-4 changes vs the 108us round-1 version (all ILP, same structure):
//  - ph1 loads batched 8-deep (32 independent float4 loads/thread) and the
//    8 shuffle-reduction chains run interleaved -> VMEM + LDS-pipe ILP ~8x.
//  - ph3's LLC re-read: first 8 float4s issued right after ph1's barrier so
//    they fly during the whole softmax chain; rest streamed with unroll 8.
//  - w_prev prefetched into registers at kernel entry.
//  - __launch_bounds__(1024,4) pins VGPR<=128 so 16 waves/CU is kept.
// ---------------------------------------------------------------------------
__global__ __launch_bounds__(1024, 4) void k_fused(
        const float* __restrict__ h, const float* __restrict__ Wm,
        const float* __restrict__ bias, const float* __restrict__ w_prev,
        const float* __restrict__ mem, float* __restrict__ w_out,
        float* __restrict__ mem_out) {
    __shared__ float hs[CC];
    __shared__ float os[OUTD];
    __shared__ __align__(16) float kk[MM];   // k + 1e-16
    __shared__ __align__(16) float ee[MM];   // sigmoid(e)
    __shared__ __align__(16) float aa[MM];
    __shared__ float sc[8];                  // 0:beta 1:g 2:gamma 3:knorm 4..6:s
    __shared__ float lgs[NN];                // logits, later final w
    __shared__ float wg[NN];                 // gated weights
    __shared__ float red[16];

    const int b = blockIdx.x;
    const int t = threadIdx.x;
    const int lane = t & 63;
    const int wid = t >> 6;

    // prefetch w_prev (used mid-ph2); loads stay in flight through ph0+ph1
    const float wp0 = w_prev[(size_t)b * NN + t];
    const float wp1 = w_prev[(size_t)b * NN + t + 1024];

    // ---- phase 0: controller projection (198x512 matvec) -----------------
    if (t < CC) hs[t] = h[(size_t)b * CC + t];
    __syncthreads();

    if (t < 4 * OUTD) {                      // 4 lanes per output row
        const int row = t >> 2, l4 = t & 3;
        const float* wr = Wm + (size_t)row * CC + 4 * l4;
        float acc = 0.f;
        #pragma unroll
        for (int c = 0; c < CC; c += 16) {
            const float4 p = *(const float4*)(wr + c);
            const int hb = c + 4 * l4;
            acc += p.x * hs[hb] + p.y * hs[hb + 1] + p.z * hs[hb + 2] + p.w * hs[hb + 3];
        }
        acc += __shfl_xor(acc, 1, 64);
        acc += __shfl_xor(acc, 2, 64);
        if (l4 == 0) os[row] = acc + bias[row];
    }
    __syncthreads();

    // ---- phase 0b: split + activations -----------------------------------
    if (t < 64) {
        const float kv = os[t] + 1e-16f;
        kk[t] = kv;
        float ss = kv * kv;
        #pragma unroll
        for (int off = 32; off; off >>= 1) ss += __shfl_xor(ss, off, 64);
        if (t == 0) sc[3] = sqrtf(ss);       // ||k + 1e-16||
    } else if (t < 128) {
        const int m = t - 64;
        ee[m] = sigmoidf(os[70 + m]);
        aa[m] = os[134 + m];
    } else if (t == 128) {
        sc[0] = softplusf(os[64]);           // beta
    } else if (t == 129) {
        sc[1] = sigmoidf(os[65]);            // g
    } else if (t == 130) {
        sc[2] = 1.f + softplusf(os[69]);     // gamma
    } else if (t == 131) {                   // 3-way softmax for shift weights
        const float x0 = os[66], x1 = os[67], x2 = os[68];
        const float mx = fmaxf(x0, fmaxf(x1, x2));
        const float e0 = expf(x0 - mx), e1 = expf(x1 - mx), e2 = expf(x2 - mx);
        const float inv = 1.f / (e0 + e1 + e2);
        sc[4] = e0 * inv; sc[5] = e1 * inv; sc[6] = e2 * inv;
    }
    __syncthreads();

    // ---- phase 1: content-addressing logits (8-deep load batches) --------
    {
        const int l = t & 15, grp = t >> 4;  // 64 groups of 16 lanes
        const float kv0 = kk[4 * l + 0], kv1 = kk[4 * l + 1];
        const float kv2 = kk[4 * l + 2], kv3 = kk[4 * l + 3];
        const float beta = sc[0], knorm = sc[3];
        const float* mb = mem + (size_t)b * NN * MM;
        #pragma unroll
        for (int o = 0; o < 4; ++o) {
            float4 pv[8];
            #pragma unroll
            for (int i = 0; i < 8; ++i)
                pv[i] = *(const float4*)(mb + (size_t)(o * 512 + i * 64 + grp) * MM + 4 * l);
            float dot[8], ssv[8];
            #pragma unroll
            for (int i = 0; i < 8; ++i) {
                const float m0 = pv[i].x + 1e-16f, m1 = pv[i].y + 1e-16f;
                const float m2 = pv[i].z + 1e-16f, m3 = pv[i].w + 1e-16f;
                dot[i] = m0 * kv0 + m1 * kv1 + m2 * kv2 + m3 * kv3;
                ssv[i] = m0 * m0 + m1 * m1 + m2 * m2 + m3 * m3;
            }
            #pragma unroll
            for (int off = 1; off < 16; off <<= 1) {
                #pragma unroll
                for (int i = 0; i < 8; ++i) {
                    dot[i] += __shfl_xor(dot[i], off, 64);
                    ssv[i] += __shfl_xor(ssv[i], off, 64);
                }
            }
            if (l == 0) {
                #pragma unroll
                for (int i = 0; i < 8; ++i)
                    lgs[o * 512 + i * 64 + grp] =
                        beta * dot[i] / fmaxf(sqrtf(ssv[i]) * knorm, 1e-8f);
            }
        }
    }
    __syncthreads();

    // ---- preload first 8 ph3 re-read tiles; in flight during all of ph2 --
    const float* mb3 = mem + (size_t)b * NN * MM + 4 * t;
    float4 pre[8];
    #pragma unroll
    for (int i = 0; i < 8; ++i) pre[i] = *(const float4*)(mb3 + (size_t)i * 4096);

    // ---- phase 2: softmax -> gate -> shift -> sharpen -> normalize -------
    const float g = sc[1], gamma = sc[2];
    const float s0 = sc[4], s1 = sc[5], s2 = sc[6];

    float v0 = lgs[t], v1 = lgs[t + 1024];
    float lmax = fmaxf(v0, v1);
    #pragma unroll
    for (int off = 32; off; off >>= 1) lmax = fmaxf(lmax, __shfl_xor(lmax, off, 64));
    if (lane == 0) red[wid] = lmax;
    __syncthreads();
    float mx = red[0];
    #pragma unroll
    for (int i = 1; i < 16; ++i) mx = fmaxf(mx, red[i]);
    __syncthreads();

    v0 = expf(v0 - mx); v1 = expf(v1 - mx);
    float lsum = v0 + v1;
    #pragma unroll
    for (int off = 32; off; off >>= 1) lsum += __shfl_xor(lsum, off, 64);
    if (lane == 0) red[wid] = lsum;
    __syncthreads();
    float tot = 0.f;
    #pragma unroll
    for (int i = 0; i < 16; ++i) tot += red[i];
    __syncthreads();
    const float inv = 1.f / tot;

    wg[t]        = g * (v0 * inv) + (1.f - g) * wp0;
    wg[t + 1024] = g * (v1 * inv) + (1.f - g) * wp1;
    __syncthreads();

    float ws0, ws1;
    {
        const int n0 = t;
        const float wt0 = wg[(n0 + NN - 1) & (NN - 1)] * s0 + wg[n0] * s1
                        + wg[(n0 + 1) & (NN - 1)] * s2;
        ws0 = (wt0 > 0.f) ? exp2f(gamma * log2f(wt0)) : 0.f;
        const int n1 = t + 1024;
        const float wt1 = wg[(n1 - 1) & (NN - 1)] * s0 + wg[n1] * s1
                        + wg[(n1 + 1) & (NN - 1)] * s2;
        ws1 = (wt1 > 0.f) ? exp2f(gamma * log2f(wt1)) : 0.f;
    }
    float psum = ws0 + ws1;
    #pragma unroll
    for (int off = 32; off; off >>= 1) psum += __shfl_xor(psum, off, 64);
    if (lane == 0) red[wid] = psum;
    __syncthreads();
    float ptot = 0.f;
    #pragma unroll
    for (int i = 0; i < 16; ++i) ptot += red[i];
    const float invp = 1.f / (ptot + 1e-16f);

    const float wf0 = ws0 * invp, wf1 = ws1 * invp;
    lgs[t] = wf0;                              // reuse lgs as final-w buffer
    lgs[t + 1024] = wf1;
    w_out[(size_t)b * NN + t] = wf0;
    w_out[(size_t)b * NN + t + 1024] = wf1;
    __syncthreads();

    // ---- phase 3: erase/add memory write ---------------------------------
    {
        const int m0 = 4 * (t & 15);          // fixed per thread across iters
        const vf4 ev = *(const vf4*)(ee + m0);
        const vf4 av = *(const vf4*)(aa + m0);
        float* ob = mem_out + (size_t)b * NN * MM + 4 * t;

        #pragma unroll
        for (int i = 0; i < 8; ++i) {          // preloaded tiles
            const float w = lgs[i * 64 + (t >> 4)];
            const float4 p = pre[i];
            vf4 o;
            o.x = p.x * (1.f - w * ev.x) + w * av.x;
            o.y = p.y * (1.f - w * ev.y) + w * av.y;
            o.z = p.z * (1.f - w * ev.z) + w * av.z;
            o.w = p.w * (1.f - w * ev.w) + w * av.w;
            __builtin_nontemporal_store(o, (vf4*)(ob + (size_t)i * 4096));
        }
        #pragma unroll 8
        for (int it = 8; it < 32; ++it) {      // streamed tiles (LLC-hot)
            const float w = lgs[it * 64 + (t >> 4)];
            const float4 p = *(const float4*)(mb3 + (size_t)it * 4096);
            vf4 o;
            o.x = p.x * (1.f - w * ev.x) + w * av.x;
            o.y = p.y * (1.f - w * ev.y) + w * av.y;
            o.z = p.z * (1.f - w * ev.z) + w * av.z;
            o.w = p.w * (1.f - w * ev.w) + w * av.w;
            __builtin_nontemporal_store(o, (vf4*)(ob + (size_t)it * 4096));
        }
    }
}

extern "C" void kernel_launch(void* const* d_in, const int* in_sizes, int n_in,
                              void* d_out, int out_size, void* d_ws, size_t ws_size,
                              hipStream_t stream) {
    const float* h      = (const float*)d_in[0];
    const float* w_prev = (const float*)d_in[1];
    const float* memory = (const float*)d_in[2];
    const float* W      = (const float*)d_in[3];
    const float* bias   = (const float*)d_in[4];
    float* out = (float*)d_out;

    float* w_out   = out;                       // [B,N]
    float* mem_out = out + (size_t)BB * NN;     // [B,N,M]

    k_fused<<<BB, 1024, 0, stream>>>(h, W, bias, w_prev, memory, w_out, mem_out);
}

// Round 5
// 268.998 us; speedup vs baseline: 1.7857x; 1.0000x over previous
//
#include <hip/hip_runtime.h>
#include <stdint.h>

// Problem constants
#define BB   256
#define NN   2048
#define MM   64
#define CC   512
#define OUTD 198

#define CHUNK_F 4096              // floats per chunk = 16 KB = 64 rows
#define NCH     32                // chunks per batch (512 KB / 16 KB)

typedef float vf4 __attribute__((ext_vector_type(4)));

__device__ __forceinline__ float softplusf(float x) {
    return x > 20.f ? x : log1pf(expf(x));
}
__device__ __forceinline__ float sigmoidf(float x) {
    return 1.f / (1.f + expf(-x));
}

// async global->LDS DMA, 16B per lane. LDS dest is wave-uniform base; HW adds
// lane*16. Global src is per-lane.
__device__ __forceinline__ void dma16(const float* g, float* l) {
    __builtin_amdgcn_global_load_lds(
        (const __attribute__((address_space(1))) uint32_t*)g,
        (__attribute__((address_space(3))) uint32_t*)l, 16, 0, 0);
}

// Raw barrier: waits LDS ops only (lgkmcnt), does NOT drain vmcnt -> in-flight
// global_load_lds prefetches survive phase boundaries (unlike __syncthreads,
// which emits s_waitcnt vmcnt(0) and restarts the memory pipeline).
__device__ __forceinline__ void bar_lds() {
    asm volatile("s_waitcnt lgkmcnt(0)" ::: "memory");
    __builtin_amdgcn_sched_barrier(0);
    __builtin_amdgcn_s_barrier();
    __builtin_amdgcn_sched_barrier(0);
}

// ---------------------------------------------------------------------------
// Fused NTM write head, continuous-stream version. One block/batch, 16 waves.
// Each wave runs a private DMA pipeline (stages + consumes its own 1KB slice
// of each 16KB chunk) with counted vmcnt waits -> no barriers inside the two
// streaming phases, loads in flight across ALL phase boundaries.
// ---------------------------------------------------------------------------
__global__ __launch_bounds__(1024, 4) void k_fused(
        const float* __restrict__ h, const float* __restrict__ Wm,
        const float* __restrict__ bias, const float* __restrict__ w_prev,
        const float* __restrict__ mem, float* __restrict__ w_out,
        float* __restrict__ mem_out) {
    __shared__ __align__(16) float stage[2][CHUNK_F];   // 32 KB DMA stage
    __shared__ float hs[CC];
    __shared__ float os[OUTD];
    __shared__ __align__(16) float kk[MM];   // k + 1e-16
    __shared__ __align__(16) float ee[MM];   // sigmoid(e)
    __shared__ __align__(16) float aa[MM];
    __shared__ float sc[8];                  // 0:beta 1:g 2:gamma 3:knorm 4..6:s
    __shared__ float lgs[NN];                // logits, later final w
    __shared__ float wg[NN];                 // gated weights
    __shared__ float wprev_s[NN];            // w_prev parked in LDS
    __shared__ float red[16];

    const int b  = blockIdx.x;
    const int t  = threadIdx.x;
    const int ln = t & 63;                   // lane
    const int wv = t >> 6;                   // wave id (0..15)
    const int seg  = ln & 15;                // 16B segment within a row
    const int rsub = ln >> 4;                // row within wave's 4-row slice

    const float* mb = mem + (size_t)b * (NN * MM);

    // ---- kernel prologue: loads first (FIFO order matters), then DMAs ----
    float hv = 0.f;
    if (t < CC) hv = h[(size_t)b * CC + t];
    const float wp0 = w_prev[(size_t)b * NN + t];
    const float wp1 = w_prev[(size_t)b * NN + t + 1024];
    // issue ph1 chunks 0,1 -> HBM busy from cycle ~0, lands during ph0
    dma16(mb + 0 * CHUNK_F + wv * 256 + ln * 4, &stage[0][wv * 256]);
    dma16(mb + 1 * CHUNK_F + wv * 256 + ln * 4, &stage[1][wv * 256]);
    // park h and w_prev in LDS (waits vmcnt only down to the DMAs)
    if (t < CC) hs[t] = hv;
    wprev_s[t] = wp0;
    wprev_s[t + 1024] = wp1;
    bar_lds();

    // ---- phase 0: controller projection (198x512 matvec) -----------------
    if (t < 4 * OUTD) {                      // 4 lanes per output row
        const int row = t >> 2, l4 = t & 3;
        const float* wr = Wm + (size_t)row * CC + 4 * l4;
        float acc = 0.f;
        #pragma unroll
        for (int c = 0; c < CC; c += 16) {
            const float4 p = *(const float4*)(wr + c);
            const int hb = c + 4 * l4;
            acc += p.x * hs[hb] + p.y * hs[hb + 1] + p.z * hs[hb + 2] + p.w * hs[hb + 3];
        }
        acc += __shfl_xor(acc, 1, 64);
        acc += __shfl_xor(acc, 2, 64);
        if (l4 == 0) os[row] = acc + bias[row];
    }
    bar_lds();

    // ---- phase 0b: split + activations -----------------------------------
    if (t < 64) {
        const float kv = os[t] + 1e-16f;
        kk[t] = kv;
        float ss = kv * kv;
        #pragma unroll
        for (int off = 32; off; off >>= 1) ss += __shfl_xor(ss, off, 64);
        if (t == 0) sc[3] = sqrtf(ss);       // ||k + 1e-16||
    } else if (t < 128) {
        const int m = t - 64;
        ee[m] = sigmoidf(os[70 + m]);
        aa[m] = os[134 + m];
    } else if (t == 128) {
        sc[0] = softplusf(os[64]);           // beta
    } else if (t == 129) {
        sc[1] = sigmoidf(os[65]);            // g
    } else if (t == 130) {
        sc[2] = 1.f + softplusf(os[69]);     // gamma
    } else if (t == 131) {                   // 3-way softmax for shift weights
        const float x0 = os[66], x1 = os[67], x2 = os[68];
        const float mx = fmaxf(x0, fmaxf(x1, x2));
        const float e0 = expf(x0 - mx), e1 = expf(x1 - mx), e2 = expf(x2 - mx);
        const float inv = 1.f / (e0 + e1 + e2);
        sc[4] = e0 * inv; sc[5] = e1 * inv; sc[6] = e2 * inv;
    }
    bar_lds();

    // ---- phase 1: content logits, per-wave DMA pipeline (no barriers) ----
    {
        const float kv0 = kk[4 * seg + 0], kv1 = kk[4 * seg + 1];
        const float kv2 = kk[4 * seg + 2], kv3 = kk[4 * seg + 3];
        const float beta = sc[0], knorm = sc[3];
        for (int c = 0; c < NCH; ++c) {
            if (c < NCH - 1) { asm volatile("s_waitcnt vmcnt(1)" ::: "memory"); }
            else             { asm volatile("s_waitcnt vmcnt(0)" ::: "memory"); }
            __builtin_amdgcn_sched_barrier(0);
            const float4 p = *(const float4*)&stage[c & 1][wv * 256 + ln * 4];
            const float m0 = p.x + 1e-16f, m1 = p.y + 1e-16f;
            const float m2 = p.z + 1e-16f, m3 = p.w + 1e-16f;
            float dot = m0 * kv0 + m1 * kv1 + m2 * kv2 + m3 * kv3;
            float ss  = m0 * m0 + m1 * m1 + m2 * m2 + m3 * m3;
            #pragma unroll
            for (int off = 1; off < 16; off <<= 1) {
                dot += __shfl_xor(dot, off, 64);
                ss  += __shfl_xor(ss,  off, 64);
            }
            if (seg == 0)
                lgs[c * 64 + wv * 4 + rsub] =
                    beta * dot / fmaxf(sqrtf(ss) * knorm, 1e-8f);
            if (c + 2 < NCH)
                dma16(mb + (size_t)(c + 2) * CHUNK_F + wv * 256 + ln * 4,
                      &stage[c & 1][wv * 256]);
        }
    }
    // issue ph3 chunks 0,1 (LLC-hot re-read) BEFORE the softmax barrier ->
    // they fly during all of ph2 (raw barriers don't drain vmcnt).
    dma16(mb + 0 * CHUNK_F + wv * 256 + ln * 4, &stage[0][wv * 256]);
    dma16(mb + 1 * CHUNK_F + wv * 256 + ln * 4, &stage[1][wv * 256]);
    bar_lds();

    // ---- phase 2: softmax -> gate -> shift -> sharpen -> normalize -------
    const float g = sc[1], gamma = sc[2];
    const float s0 = sc[4], s1 = sc[5], s2 = sc[6];

    float v0 = lgs[t], v1 = lgs[t + 1024];
    float lmax = fmaxf(v0, v1);
    #pragma unroll
    for (int off = 32; off; off >>= 1) lmax = fmaxf(lmax, __shfl_xor(lmax, off, 64));
    if (ln == 0) red[wv] = lmax;
    bar_lds();
    float mx = red[0];
    #pragma unroll
    for (int i = 1; i < 16; ++i) mx = fmaxf(mx, red[i]);
    bar_lds();

    v0 = expf(v0 - mx); v1 = expf(v1 - mx);
    float lsum = v0 + v1;
    #pragma unroll
    for (int off = 32; off; off >>= 1) lsum += __shfl_xor(lsum, off, 64);
    if (ln == 0) red[wv] = lsum;
    bar_lds();
    float tot = 0.f;
    #pragma unroll
    for (int i = 0; i < 16; ++i) tot += red[i];
    bar_lds();
    const float inv = 1.f / tot;

    wg[t]        = g * (v0 * inv) + (1.f - g) * wprev_s[t];
    wg[t + 1024] = g * (v1 * inv) + (1.f - g) * wprev_s[t + 1024];
    bar_lds();

    float ws0, ws1;
    {
        const int n0 = t;
        const float wt0 = wg[(n0 + NN - 1) & (NN - 1)] * s0 + wg[n0] * s1
                        + wg[(n0 + 1) & (NN - 1)] * s2;
        ws0 = (wt0 > 0.f) ? exp2f(gamma * log2f(wt0)) : 0.f;
        const int n1 = t + 1024;
        const float wt1 = wg[(n1 - 1) & (NN - 1)] * s0 + wg[n1] * s1
                        + wg[(n1 + 1) & (NN - 1)] * s2;
        ws1 = (wt1 > 0.f) ? exp2f(gamma * log2f(wt1)) : 0.f;
    }
    float psum = ws0 + ws1;
    #pragma unroll
    for (int off = 32; off; off >>= 1) psum += __shfl_xor(psum, off, 64);
    if (ln == 0) red[wv] = psum;
    bar_lds();
    float ptot = 0.f;
    #pragma unroll
    for (int i = 0; i < 16; ++i) ptot += red[i];
    const float invp = 1.f / (ptot + 1e-16f);

    const float wf0 = ws0 * invp, wf1 = ws1 * invp;
    lgs[t] = wf0;                              // reuse lgs as final-w buffer
    lgs[t + 1024] = wf1;
    w_out[(size_t)b * NN + t] = wf0;
    w_out[(size_t)b * NN + t + 1024] = wf1;
    bar_lds();

    // ---- phase 3: erase/add write, per-wave DMA pipeline (no barriers) ---
    {
        const vf4 ev = *(const vf4*)&ee[4 * seg];
        const vf4 av = *(const vf4*)&aa[4 * seg];
        float* ob = mem_out + (size_t)b * (NN * MM);
        for (int c = 0; c < NCH; ++c) {
            // vmcnt(2): FIFO holds {dma c, dma c+1, <=1 old NT store} ->
            // <=2 outstanding guarantees dma(c) landed. Last iter drains.
            if (c < NCH - 1) { asm volatile("s_waitcnt vmcnt(2)" ::: "memory"); }
            else             { asm volatile("s_waitcnt vmcnt(0)" ::: "memory"); }
            __builtin_amdgcn_sched_barrier(0);
            const float wq = lgs[c * 64 + wv * 4 + rsub];   // LDS broadcast
            const float4 p = *(const float4*)&stage[c & 1][wv * 256 + ln * 4];
            vf4 o;
            o.x = p.x * (1.f - wq * ev.x) + wq * av.x;
            o.y = p.y * (1.f - wq * ev.y) + wq * av.y;
            o.z = p.z * (1.f - wq * ev.z) + wq * av.z;
            o.w = p.w * (1.f - wq * ev.w) + wq * av.w;
            __builtin_nontemporal_store(
                o, (vf4*)(ob + (size_t)c * CHUNK_F + wv * 256 + ln * 4));
            if (c + 2 < NCH)
                dma16(mb + (size_t)(c + 2) * CHUNK_F + wv * 256 + ln * 4,
                      &stage[c & 1][wv * 256]);
        }
    }
}

extern "C" void kernel_launch(void* const* d_in, const int* in_sizes, int n_in,
                              void* d_out, int out_size, void* d_ws, size_t ws_size,
                              hipStream_t stream) {
    const float* h      = (const float*)d_in[0];
    const float* w_prev = (const float*)d_in[1];
    const float* memory = (const float*)d_in[2];
    const float* W      = (const float*)d_in[3];
    const float* bias   = (const float*)d_in[4];
    float* out = (float*)d_out;

    float* w_out   = out;                       // [B,N]
    float* mem_out = out + (size_t)BB * NN;     // [B,N,M]

    k_fused<<<BB, 1024, 0, stream>>>(h, W, bias, w_prev, memory, w_out, mem_out);
}